// Round 5
// baseline (59.750 us; speedup 1.0000x reference)
//
#include <hip/hip_runtime.h>
#include <hip/hip_bf16.h>

#define MDIM 8192
#define KDIM 256
#define NB 32        // 8192/256 tiles per dim
#define NTILES 528   // NB*(NB+1)/2 upper-triangle tiles
#define GRID 256     // persistent blocks, 1 per CU (128 KB LDS)

typedef __attribute__((ext_vector_type(8))) short short8;
typedef __attribute__((ext_vector_type(4))) float f32x4;

__device__ __forceinline__ ushort bf16u(float f) {
    __hip_bfloat16 h = __float2bfloat16(f);
    return *reinterpret_cast<ushort*>(&h);
}

// async global->LDS, 16B per lane; LDS dest = wave-uniform base + lane*16.
__device__ __forceinline__ void async16(ushort* lds, const ushort* g) {
    __builtin_amdgcn_global_load_lds(
        (const __attribute__((address_space(1))) void*)g,
        (__attribute__((address_space(3))) void*)lds, 16, 0, 0);
}

// Kernel 1: each wave owns the row pair (i, i+4096): normalizes both rows to bf16,
// computes pos[i] = pos[i+4096] = 10*cos(x_i, x_p) in fp32, zeros row_sum.
__global__ __launch_bounds__(256) void knorm(const float* __restrict__ x,
                                             ushort* __restrict__ xn,
                                             float* __restrict__ row_sum,
                                             float* __restrict__ pos) {
    const int wave = threadIdx.x >> 6, lane = threadIdx.x & 63;
    const int i = blockIdx.x * 4 + wave;  // 0..4095
    const int p = i + 4096;
    const float4 a = *reinterpret_cast<const float4*>(x + (size_t)i * KDIM + lane * 4);
    const float4 b = *reinterpret_cast<const float4*>(x + (size_t)p * KDIM + lane * 4);
    float sa = a.x * a.x + a.y * a.y + a.z * a.z + a.w * a.w;
    float sb = b.x * b.x + b.y * b.y + b.z * b.z + b.w * b.w;
    float sab = a.x * b.x + a.y * b.y + a.z * b.z + a.w * b.w;
#pragma unroll
    for (int m = 1; m < 64; m <<= 1) {
        sa += __shfl_xor(sa, m, 64);
        sb += __shfl_xor(sb, m, 64);
        sab += __shfl_xor(sab, m, 64);
    }
    const float ia = 1.0f / fmaxf(sqrtf(sa), 1e-8f);
    const float ib = 1.0f / fmaxf(sqrtf(sb), 1e-8f);
    ushort4 oa, ob;
    oa.x = bf16u(a.x * ia); oa.y = bf16u(a.y * ia);
    oa.z = bf16u(a.z * ia); oa.w = bf16u(a.w * ia);
    ob.x = bf16u(b.x * ib); ob.y = bf16u(b.y * ib);
    ob.z = bf16u(b.z * ib); ob.w = bf16u(b.w * ib);
    *reinterpret_cast<ushort4*>(xn + (size_t)i * KDIM + lane * 4) = oa;
    *reinterpret_cast<ushort4*>(xn + (size_t)p * KDIM + lane * 4) = ob;
    if (lane == 0) {
        const float pv = 10.0f * sab * ia * ib;
        pos[i] = pv;
        pos[p] = pv;
    }
    if (threadIdx.x < 8) row_sum[blockIdx.x * 8 + threadIdx.x] = 0.0f;
}

// Kernel 2: persistent blocks (1/CU), each owns 2-3 upper-triangle 256x256 tiles.
// 8 waves (2Mx4N), per-wave 128x64 output = acc[8][4] f32x4. Flat double-buffered
// global_load_lds pipeline across K-tiles of 64 and tile boundaries, counted
// vmcnt(8). Per K-tile per wave: 8 B-frag + 16 A-frag ds_read_b128 -> 64 MFMA
// (ratio 2.67: MFMA-bound, LDS pipe just under). Source-swizzled staging (rule 21,
// involution verified conflict-free R2-R4). Symmetric row+col exp-sum fold.
__global__ __launch_bounds__(512, 2) void ksim(const ushort* __restrict__ xn,
                                               float* __restrict__ row_sum) {
    __shared__ ushort As[2][16384];  // 256 rows x 64 cols, x2 buf
    __shared__ ushort Bs[2][16384];

    const int blk = blockIdx.x;
    const int tb0 = (blk * 33) >> 4;          // blk * 528 / 256
    const int tend = ((blk + 1) * 33) >> 4;
    const int S = 4 * (tend - tb0);           // flat K-tile steps for this block

    // decode tb0 -> (bi, bj) in row-major upper triangle (NB=32)
    int bi = (int)((65.0f - sqrtf(4225.0f - 8.0f * (float)tb0)) * 0.5f);
    while (NB * bi - bi * (bi - 1) / 2 > tb0) --bi;
    while (NB * (bi + 1) - (bi + 1) * bi / 2 <= tb0) ++bi;
    int bj = bi + (tb0 - (NB * bi - bi * (bi - 1) / 2));

    const int t = threadIdx.x;
    const int wave = t >> 6, lane = t & 63;
    const int l16 = lane & 15, lhi = lane >> 4;
    const int wr = wave >> 2, wc = wave & 3;
    const int wRow = wr * 128, wCol = wc * 64;

    // staging: round q covers tile rows [q*64, q*64+64); within a round, wave w
    // writes rows q*64 + w*8 + (lane>>3), cols (lane&7)*8 -- LDS dest is linear
    // (base + lane*16B); global source col carries the XOR involution.
    const int srcc = 8 * ((lane & 7) ^ (lane >> 3));
    const int roff = (wave * 8 + (lane >> 3)) * KDIM + srcc;  // ushort units
    const int sw = (l16 & 7) << 3;  // matching swizzle on ds_read

    int sbi = bi, sbj = bj, sc = 0, sstep = 0;
    auto stage1 = [&]() {
        const ushort* Ab = xn + (size_t)sbi * 256 * KDIM + sc * 64 + roff;
        const ushort* Bb = xn + (size_t)sbj * 256 * KDIM + sc * 64 + roff;
        const int buf = sstep & 1;
#pragma unroll
        for (int q = 0; q < 4; ++q)
            async16(&As[buf][q * 4096 + wave * 512], Ab + q * 64 * KDIM);
#pragma unroll
        for (int q = 0; q < 4; ++q)
            async16(&Bs[buf][q * 4096 + wave * 512], Bb + q * 64 * KDIM);
        ++sstep;
        if (++sc == 4) {
            sc = 0;
            if (++sbj == NB) { ++sbi; sbj = sbi; }
        }
    };

    f32x4 acc[8][4];
#pragma unroll
    for (int m = 0; m < 8; ++m)
#pragma unroll
        for (int n = 0; n < 4; ++n) acc[m][n] = (f32x4){0.f, 0.f, 0.f, 0.f};

    auto compute = [&](int buf) {
        short8 bf[4][2];
#pragma unroll
        for (int n = 0; n < 4; ++n)
#pragma unroll
            for (int k2 = 0; k2 < 2; ++k2)
                bf[n][k2] = *reinterpret_cast<const short8*>(
                    &Bs[buf][(wCol + n * 16 + l16) * 64 + ((k2 * 32 + lhi * 8) ^ sw)]);
        __builtin_amdgcn_s_setprio(1);
#pragma unroll
        for (int m = 0; m < 8; ++m) {
            const int r = (wRow + m * 16 + l16) * 64;
            const short8 a0 = *reinterpret_cast<const short8*>(&As[buf][r + ((lhi * 8) ^ sw)]);
            const short8 a1 = *reinterpret_cast<const short8*>(&As[buf][r + ((32 + lhi * 8) ^ sw)]);
#pragma unroll
            for (int n = 0; n < 4; ++n) {
                acc[m][n] = __builtin_amdgcn_mfma_f32_16x16x32_bf16(a0, bf[n][0], acc[m][n], 0, 0, 0);
                acc[m][n] = __builtin_amdgcn_mfma_f32_16x16x32_bf16(a1, bf[n][1], acc[m][n], 0, 0, 0);
            }
        }
        __builtin_amdgcn_s_setprio(0);
    };

    stage1();  // step 0
    stage1();  // step 1
    int cstep = 0;

    for (int tt = tb0; tt < tend; ++tt) {
        for (int c = 0; c < 4; ++c, ++cstep) {
            if (cstep == S - 1)
                asm volatile("s_waitcnt vmcnt(0)\n\ts_barrier" ::: "memory");
            else
                asm volatile("s_waitcnt vmcnt(8)\n\ts_barrier" ::: "memory");
            compute(cstep & 1);
            asm volatile("s_barrier" ::: "memory");
            if (sstep < S) stage1();  // into the buffer just freed
        }

        // ---- tile epilogue (registers only; overlaps in-flight loads) ----
        const bool diag = (bi == bj);
        float csum[4] = {0.f, 0.f, 0.f, 0.f};
#pragma unroll
        for (int m = 0; m < 8; ++m) {
            float psum[4] = {0.f, 0.f, 0.f, 0.f};
#pragma unroll
            for (int n = 0; n < 4; ++n)
#pragma unroll
                for (int j = 0; j < 4; ++j) {
                    float e = __expf(acc[m][n][j] * 10.0f);
                    if (diag && (wRow + m * 16 + lhi * 4 + j) == (wCol + n * 16 + l16))
                        e = 0.0f;
                    psum[j] += e;
                    csum[n] += e;
                    acc[m][n][j] = 0.0f;  // fused re-zero for next tile
                }
#pragma unroll
            for (int j = 0; j < 4; ++j) {
                float s = psum[j];
                s += __shfl_xor(s, 1, 16);
                s += __shfl_xor(s, 2, 16);
                s += __shfl_xor(s, 4, 16);
                s += __shfl_xor(s, 8, 16);
                if (l16 == 0)
                    atomicAdd(&row_sum[bi * 256 + wRow + m * 16 + lhi * 4 + j], s);
            }
        }
        if (!diag) {
#pragma unroll
            for (int n = 0; n < 4; ++n) {
                float s = csum[n];
                s += __shfl_xor(s, 16, 64);
                s += __shfl_xor(s, 32, 64);
                if (lhi == 0)
                    atomicAdd(&row_sum[bj * 256 + wCol + n * 16 + l16], s);
            }
        }

        if (++bj == NB) { ++bi; bj = bi; }
    }
}

// Kernel 3: loss = mean_i( log(row_sum[i]) - pos[i] )
__global__ __launch_bounds__(1024) void kfinal(const float* __restrict__ row_sum,
                                               const float* __restrict__ pos,
                                               float* __restrict__ out) {
    float acc = 0.f;
    for (int i = threadIdx.x; i < MDIM; i += 1024)
        acc += logf(row_sum[i]) - pos[i];
#pragma unroll
    for (int m = 1; m < 64; m <<= 1) acc += __shfl_xor(acc, m, 64);
    __shared__ float w[16];
    if ((threadIdx.x & 63) == 0) w[threadIdx.x >> 6] = acc;
    __syncthreads();
    if (threadIdx.x == 0) {
        float s = 0.f;
#pragma unroll
        for (int i = 0; i < 16; ++i) s += w[i];
        out[0] = s / (float)MDIM;
    }
}

extern "C" void kernel_launch(void* const* d_in, const int* in_sizes, int n_in,
                              void* d_out, int out_size, void* d_ws, size_t ws_size,
                              hipStream_t stream) {
    const float* x = (const float*)d_in[0];
    float* out = (float*)d_out;

    char* ws = (char*)d_ws;
    ushort* xn = (ushort*)ws;                                  // 8192*256*2 = 4 MB
    float* row_sum = (float*)(ws + (size_t)MDIM * KDIM * 2);   // 32 KB
    float* pos = row_sum + MDIM;                               // 32 KB

    knorm<<<MDIM / 8, 256, 0, stream>>>(x, xn, row_sum, pos);
    ksim<<<GRID, 512, 0, stream>>>(xn, row_sum);
    kfinal<<<1, 1024, 0, stream>>>(row_sum, pos, out);
}